// Round 8
// baseline (206.318 us; speedup 1.0000x reference)
//
#include <hip/hip_runtime.h>
#include <stdint.h>

#define EPS 1e-5f
#define LOG2E 1.4426950408889634f

// ---------------- problem constants ----------------
#define NPTS 80000
#define CDIM 128
#define ODIM 64
#define KNBR 8
#define MSUP 1000

// ---------------- workspace layout (bytes) ----------------
#define KP2H_OFF 0                 // [1000][128] bf16 = 256 KB (BN1-folded k+pe table)
#define UT_OFF   (256*1024)        // [1000][64]  f32  = 256 KB (LOG2E-scaled, INTERLEAVED)
#define WQF_OFF  (512*1024)        // 32 frags * 1KB = 32 KB (Wq*s1c, A-layout)
#define W1F_OFF  (544*1024)        // 16 frags * 1KB = 16 KB (W1*s2c, A-layout)
#define W2F_OFF  (560*1024)        // 8 frags * 1KB  = 8 KB  (W2*LOG2E, B-layout)
#define C1_OFF   (568*1024)        // [64] f32 ((b1-m2)*s2c + beta2)
#define WSTAGE_BYTES (16*1024 + 8*1024 + 256)   // 24832 (W1F..C1 contiguous blob)

typedef float f32x4 __attribute__((ext_vector_type(4)));
typedef short bf16x8 __attribute__((ext_vector_type(8)));
typedef __bf16 bf16v8 __attribute__((ext_vector_type(8)));
typedef __bf16 bf16v4 __attribute__((ext_vector_type(4)));

union FragU { bf16x8 v; unsigned u[4]; uint4 q; };

#if __has_builtin(__builtin_amdgcn_cvt_pk_bf16_f32)
#define HAVE_PK_BF16 1
#endif

__device__ inline unsigned pk_bf16(float lo, float hi) {
#ifdef HAVE_PK_BF16
  typedef __bf16 bf16x2_t __attribute__((ext_vector_type(2)));
  return __builtin_bit_cast(unsigned, __builtin_amdgcn_cvt_pk_bf16_f32(lo, hi));
#else
  unsigned a = __builtin_bit_cast(unsigned, lo);
  unsigned b = __builtin_bit_cast(unsigned, hi);
  a += 0x7FFFu + ((a >> 16) & 1u);
  b += 0x7FFFu + ((b >> 16) & 1u);
  return (a >> 16) | (b & 0xFFFF0000u);
#endif
}

__device__ inline float exp2_fast(float x) {
#if __has_builtin(__builtin_amdgcn_exp2f)
  return __builtin_amdgcn_exp2f(x);
#else
  return exp2f(x);
#endif
}

// ============================================================
// Kernel 1 (prep): blocks 0..999 per-superpoint tables; 1000..1014 weight swizzle.
// ============================================================
__global__ __launch_bounds__(256)
void k_prep(const float* __restrict__ sp_fea, const float* __restrict__ sp_xyz,
            const float* __restrict__ Wk, const float* __restrict__ bk,
            const float* __restrict__ Wv, const float* __restrict__ bv,
            const float* __restrict__ Wp1, const float* __restrict__ bp1,
            const float* __restrict__ gp, const float* __restrict__ betap,
            const float* __restrict__ mp, const float* __restrict__ vp,
            const float* __restrict__ Wp2, const float* __restrict__ bp2,
            const float* __restrict__ g1, const float* __restrict__ beta1,
            const float* __restrict__ m1, const float* __restrict__ v1,
            const float* __restrict__ bq,
            const float* __restrict__ Wq, const float* __restrict__ W1,
            const float* __restrict__ W2,
            const float* __restrict__ g2, const float* __restrict__ v2,
            const float* __restrict__ b1, const float* __restrict__ m2,
            const float* __restrict__ beta2, char* __restrict__ ws)
{
  if (blockIdx.x < 1000) {
    unsigned short* kp2h = (unsigned short*)(ws + KP2H_OFF);
    float* uT = (float*)(ws + UT_OFF);
    const int m = blockIdx.x;
    const int t = threadIdx.x;
    const int c = t & 127, half = t >> 7;
    __shared__ float fea[128];
    __shared__ float pk[128], pv[128];
    if (t < 128) fea[t] = sp_fea[m * 128 + t];
    __syncthreads();
    float kv = 0.f, vv = 0.f;
    const float* wkc = Wk + half * 64 * 128 + c;
    const float* wvc = Wv + half * 64 * 128 + c;
    const float* feah = fea + half * 64;
    #pragma unroll 8
    for (int d = 0; d < 64; ++d) {
      const float f = feah[d];
      kv = fmaf(f, wkc[d * 128], kv);
      vv = fmaf(f, wvc[d * 128], vv);
    }
    if (half) { pk[c] = kv; pv[c] = vv; }
    __syncthreads();
    if (!half) {
      kv += pk[c] + bk[c];
      vv += pv[c] + bv[c];
      const float x0 = sp_xyz[m*3+0], x1 = sp_xyz[m*3+1], x2 = sp_xyz[m*3+2];
      float pe = bp2[c];
      #pragma unroll
      for (int ii = 0; ii < 3; ++ii) {
        float s = bp1[ii] + x0*Wp1[0*3+ii] + x1*Wp1[1*3+ii] + x2*Wp1[2*3+ii];
        s = (s - mp[ii]) * (gp[ii] * rsqrtf(vp[ii] + EPS)) + betap[ii];
        s = fmaxf(s, 0.0f);
        pe += s * Wp2[ii*128 + c];
      }
      const float s1c = g1[c] * rsqrtf(v1[c] + EPS);
      const float kpv = (kv + pe - m1[c] - bq[c]) * s1c + beta1[c];
      kp2h[m*128 + c] = (unsigned short)(pk_bf16(kpv, kpv) & 0xFFFFu);
      pv[c] = vv + pe;          // reuse pv as (v+pe) storage
    }
    __syncthreads();
    // interleaved store: uTi[m][t] with t=row*4+nt holds u[m][row + nt*16]
    if (t < 64) {
      const int j = (t >> 2) + (t & 3) * 16;
      uT[m*64 + t] = (pv[j] + pv[j + 64]) * LOG2E;
    }
  } else {
    const int tid = (blockIdx.x - 1000) * 256 + threadIdx.x;
    if (tid < 2048) {
      // Wqf^T A-frags: frag f = kt*8+mt ; A[m=c][k=d], Wqf[d][c]=Wq[d][c]*s1c[c]
      const int e = tid, f = e >> 6, l = e & 63;
      const int kt = f >> 3, mt = f & 7;
      const int c = mt*16 + (l & 15);
      const int d0 = kt*32 + (l >> 4)*8;
      const float sc = g1[c] * rsqrtf(v1[c] + EPS);
      uint4 u;
      u.x = pk_bf16(Wq[(d0+0)*128 + c]*sc, Wq[(d0+1)*128 + c]*sc);
      u.y = pk_bf16(Wq[(d0+2)*128 + c]*sc, Wq[(d0+3)*128 + c]*sc);
      u.z = pk_bf16(Wq[(d0+4)*128 + c]*sc, Wq[(d0+5)*128 + c]*sc);
      u.w = pk_bf16(Wq[(d0+6)*128 + c]*sc, Wq[(d0+7)*128 + c]*sc);
      *(uint4*)(ws + WQF_OFF + e*16) = u;
    } else if (tid < 3072) {
      // W1f^T A-frags: frag f = kt*4+jt ; A[m=j][k=c], W1f[c][j]=W1[c][j]*s2c[j]
      const int e = tid - 2048, f = e >> 6, l = e & 63;
      const int kt = f >> 2, jt = f & 3;
      const int j = jt*16 + (l & 15);
      const int c0 = kt*32 + (l >> 4)*8;
      const float sc = g2[j] * rsqrtf(v2[j] + EPS);
      uint4 u;
      u.x = pk_bf16(W1[(c0+0)*64 + j]*sc, W1[(c0+1)*64 + j]*sc);
      u.y = pk_bf16(W1[(c0+2)*64 + j]*sc, W1[(c0+3)*64 + j]*sc);
      u.z = pk_bf16(W1[(c0+4)*64 + j]*sc, W1[(c0+5)*64 + j]*sc);
      u.w = pk_bf16(W1[(c0+6)*64 + j]*sc, W1[(c0+7)*64 + j]*sc);
      *(uint4*)(ws + W1F_OFF + e*16) = u;
    } else if (tid < 3584) {
      // W2 B-frags scaled by LOG2E: frag f = kt2*4+nt ; B[k=j][n=j']
      const int e = tid - 3072, f = e >> 6, l = e & 63;
      const int kt2 = f >> 2, nt = f & 3;
      const int jp = nt*16 + (l & 15);
      const int j0 = kt2*32 + (l >> 4)*8;
      uint4 u;
      u.x = pk_bf16(W2[(j0+0)*64 + jp]*LOG2E, W2[(j0+1)*64 + jp]*LOG2E);
      u.y = pk_bf16(W2[(j0+2)*64 + jp]*LOG2E, W2[(j0+3)*64 + jp]*LOG2E);
      u.z = pk_bf16(W2[(j0+4)*64 + jp]*LOG2E, W2[(j0+5)*64 + jp]*LOG2E);
      u.w = pk_bf16(W2[(j0+6)*64 + jp]*LOG2E, W2[(j0+7)*64 + jp]*LOG2E);
      *(uint4*)(ws + W2F_OFF + e*16) = u;
    } else if (tid < 3648) {
      const int j = tid - 3584;
      const float sc = g2[j] * rsqrtf(v2[j] + EPS);
      ((float*)(ws + C1_OFF))[j] = (b1[j] - m2[j]) * sc + beta2[j];
    }
  }
}

// ============================================================
// Kernel 2: fused main. R7's clean codegen (R1 addressing: pitch 272/144,
// C1 in LDS, no swizzles -- the ONLY no-spill addressing scheme, verified
// across R2-R7) + ONE change: q B-frags double-buffered one group ahead
// (qpn read from LDS issued after the h2 pack, drains under GEMM2+softmax).
// This removes the ~120-150cy lgkmcnt stall from each group's critical
// path -- the main delta vs R0's 57us loop, which had the same pattern
// from global. qpc dies in GEMM1, qpn born after: allocator reuses the
// same 16 regs (R0 ran this shape at 84 VGPR, zero scratch).
// ============================================================
#define H2_PITCH 144               // bytes/row (72 bf16; 16B-aligned rows)
#define H2_SIZE  (16*144)          // 2304 B / wave
#define W1L_OFF  0
#define W2L_OFF  (16*1024)
#define C1L_OFF  (24*1024)
#define H2_BASE  24832
#define QL_OFF   (H2_BASE + 4*H2_SIZE)   // 34048 (16B aligned)
#define QL_PITCH 272                     // 256 B data + 16 B pad (16B aligned rows)
#define LDS_TOTAL (QL_OFF + 32*QL_PITCH) // 42752

__global__ __launch_bounds__(256, 3)
void k_main(const int* __restrict__ idx, const float* __restrict__ b2,
            const float* __restrict__ o_p_fea,
            const char* __restrict__ ws, float* __restrict__ out)
{
  const unsigned short* kp2h = (const unsigned short*)(ws + KP2H_OFF);
  const float* uT = (const float*)(ws + UT_OFF);

  __shared__ __align__(16) char lds[LDS_TOTAL];
  const int t = threadIdx.x;
  const int wave = t >> 6, l = t & 63;
  const int quad = l >> 4, row = l & 15;
  char* h2_w = lds + H2_BASE + wave * H2_SIZE;

  const int slot = blockIdx.x * 4 + wave;   // 0..9999 wave-slots
  const int gid0 = slot * 4;                // 4 group-tasks per wave
  const int nloc = row >> 3;

  // ---- stage weight fragments into block-shared LDS (24832 B) ----
  {
    const uint4* src = (const uint4*)(ws + W1F_OFF);
    uint4* dst = (uint4*)lds;
    #pragma unroll
    for (int i = 0; i < 7; ++i) {
      const int e = t + i * 256;
      if (e < WSTAGE_BYTES / 16) dst[e] = src[e];
    }
  }

  // ---- inline q-projection for this block's 32 points ----
  // wave w: tile = w>>1 (points blockbase + tile*16 .. +15), mts (w&1)*4..+3
  {
    const int tile = wave >> 1;
    const int mt0 = (wave & 1) * 4;
    const int nq = blockIdx.x * 32 + tile * 16 + row;
    const float* feab = o_p_fea + (size_t)nq * 128;
    f32x4 qa[4];
    #pragma unroll
    for (int mt = 0; mt < 4; ++mt) qa[mt] = (f32x4){0.f, 0.f, 0.f, 0.f};
    #pragma unroll
    for (int kt = 0; kt < 4; ++kt) {
      f32x4 fa = *(const f32x4*)(feab + kt*32 + quad*8);
      f32x4 fb = *(const f32x4*)(feab + kt*32 + quad*8 + 4);
      FragU bu;
      bu.u[0] = pk_bf16(fa[0], fa[1]);
      bu.u[1] = pk_bf16(fa[2], fa[3]);
      bu.u[2] = pk_bf16(fb[0], fb[1]);
      bu.u[3] = pk_bf16(fb[2], fb[3]);
      #pragma unroll
      for (int mt = 0; mt < 4; ++mt) {
        FragU wf;
        wf.q = *(const uint4*)(ws + WQF_OFF + (((kt*8 + mt0 + mt)*64 + l) * 16));
        qa[mt] = __builtin_amdgcn_mfma_f32_16x16x32_bf16(wf.v, bu.v, qa[mt], 0, 0, 0);
      }
    }
    // D layout: n = l&15 (= row), c = (mt0+mt)*16 + quad*4 + reg -> linear-c row store
    char* lq = lds + QL_OFF + (tile*16 + row) * QL_PITCH;
    #pragma unroll
    for (int mt = 0; mt < 4; ++mt) {
      uint2 pp;
      pp.x = pk_bf16(qa[mt][0], qa[mt][1]);
      pp.y = pk_bf16(qa[mt][2], qa[mt][3]);
      *(uint2*)(lq + (mt0 + mt)*32 + quad*8) = pp;
    }
  }

  // prefetch this wave's 4 groups' gather indices (row pattern for kp2h)
  int mr4[4];
  #pragma unroll
  for (int g = 0; g < 4; ++g) mr4[g] = idx[(gid0 + g)*16 + row];

  __syncthreads();   // weights + q staged

  f32x4 c1r[4];
  #pragma unroll
  for (int jt = 0; jt < 4; ++jt)
    c1r[jt] = *(const f32x4*)(lds + C1L_OFF + (jt*16 + quad*4)*4);
  float b2r[4];
  #pragma unroll
  for (int nt = 0; nt < 4; ++nt) b2r[nt] = b2[row + nt*16] * LOG2E;

  // ---- group-0 staging: idx (quad pattern), kp2h row, q B-frags ----
  int msc[4];
  #pragma unroll
  for (int rg = 0; rg < 4; ++rg) msc[rg] = idx[gid0*16 + quad*4 + rg];
  uint4 kfc[4];
  {
    const uint4* kr = (const uint4*)(kp2h + (size_t)mr4[0] * 128);
    #pragma unroll
    for (int kt = 0; kt < 4; ++kt) kfc[kt] = kr[kt*4 + quad];
  }
  uint4 qpc[4];
  {
    const char* lqr = lds + QL_OFF + (wave*8 + nloc) * QL_PITCH;
    #pragma unroll
    for (int kt = 0; kt < 4; ++kt)
      qpc[kt] = *(const uint4*)(lqr + (kt*4 + quad)*16);
  }

  #pragma unroll 1
  for (int g = 0; g < 4; ++g) {
    const int gid = gid0 + g;
    // prefetch next group's operands (address-known; land during compute)
    int msn[4];
    uint4 kfn[4];
    if (g < 3) {
      #pragma unroll
      for (int rg = 0; rg < 4; ++rg) msn[rg] = idx[(gid+1)*16 + quad*4 + rg];
      const uint4* kr = (const uint4*)(kp2h + (size_t)mr4[g+1] * 128);
      #pragma unroll
      for (int kt = 0; kt < 4; ++kt) kfn[kt] = kr[kt*4 + quad];
    }

    // GEMM1 (transposed): h2^T = W1f^T @ X^T ; X = relu(kp2[m] - qs[n])
    // bias c1 folded in via MFMA C-in initialization
    f32x4 a1[4];
    #pragma unroll
    for (int jt = 0; jt < 4; ++jt) a1[jt] = c1r[jt];
    #pragma unroll
    for (int kt = 0; kt < 4; ++kt) {
      const bf16v8 kv = __builtin_bit_cast(bf16v8, kfc[kt]);
      const bf16v8 qv = __builtin_bit_cast(bf16v8, qpc[kt]);
      bf16v8 z = {};
      bf16v8 x = __builtin_elementwise_max((bf16v8)(kv - qv), z);
      FragU xf;
      xf.q = __builtin_bit_cast(uint4, x);
      #pragma unroll
      for (int jt = 0; jt < 4; ++jt) {
        const bf16x8 wf = *(const bf16x8*)(lds + W1L_OFF + (kt*4+jt)*1024 + l*16);
        a1[jt] = __builtin_amdgcn_mfma_f32_16x16x32_bf16(wf, xf.v, a1[jt], 0, 0, 0);
      }
    }

    // pack + packed relu; D^T: n=row -> r, m=quad*4+reg+16*jt -> j
    #pragma unroll
    for (int jt = 0; jt < 4; ++jt) {
      uint2 pp;
      pp.x = pk_bf16(a1[jt][0], a1[jt][1]);
      pp.y = pk_bf16(a1[jt][2], a1[jt][3]);
      bf16v4 h = __builtin_bit_cast(bf16v4, pp);
      bf16v4 z4 = {};
      h = __builtin_elementwise_max(h, z4);
      pp = __builtin_bit_cast(uint2, h);
      *(uint2*)(h2_w + row*H2_PITCH + (jt*16 + quad*4)*2) = pp;
    }

    // prefetch next group's q B-frags from LDS (qpc regs freed by GEMM1;
    // latency drains under GEMM2+softmax)
    uint4 qpn[4];
    if (g < 3) {
      const char* lqr = lds + QL_OFF + (wave*8 + (g+1)*2 + nloc) * QL_PITCH;
      #pragma unroll
      for (int kt = 0; kt < 4; ++kt)
        qpn[kt] = *(const uint4*)(lqr + (kt*4 + quad)*16);
    }

    // uT loads for THIS group (consumed in softmax; issued under GEMM2)
    f32x4 u4[4];
    #pragma unroll
    for (int rg = 0; rg < 4; ++rg)
      u4[rg] = *(const f32x4*)(uT + (size_t)msc[rg] * 64 + row * 4);

    // GEMM2: s2' = h2 @ (W2*LOG2E)
    f32x4 a2[4];
    #pragma unroll
    for (int nt = 0; nt < 4; ++nt) a2[nt] = (f32x4){0.f, 0.f, 0.f, 0.f};
    #pragma unroll
    for (int kt2 = 0; kt2 < 2; ++kt2) {
      const bf16x8 af = *(const bf16x8*)(h2_w + row*H2_PITCH + kt2*64 + quad*16);
      #pragma unroll
      for (int nt = 0; nt < 4; ++nt) {
        const bf16x8 wf = *(const bf16x8*)(lds + W2L_OFF + (kt2*4+nt)*1024 + l*16);
        a2[nt] = __builtin_amdgcn_mfma_f32_16x16x32_bf16(af, wf, a2[nt], 0, 0, 0);
      }
    }
    // softmax over 8 rows/point + bi accumulation, fused per-nt
    float bi0 = 0.f, bi1 = 0.f, bi2 = 0.f, bi3 = 0.f;
    #pragma unroll
    for (int nt = 0; nt < 4; ++nt) {
      const float e0 = exp2_fast(a2[nt][0] + b2r[nt]);
      const float e1 = exp2_fast(a2[nt][1] + b2r[nt]);
      const float e2 = exp2_fast(a2[nt][2] + b2r[nt]);
      const float e3 = exp2_fast(a2[nt][3] + b2r[nt]);
      float s = e0 + e1 + e2 + e3;
      s += __shfl_xor(s, 16);
      const float rs = __builtin_amdgcn_rcpf(s);
      bi0 = fmaf(e0 * rs, u4[0][nt], bi0);
      bi1 = fmaf(e1 * rs, u4[1][nt], bi1);
      bi2 = fmaf(e2 * rs, u4[2][nt], bi2);
      bi3 = fmaf(e3 * rs, u4[3][nt], bi3);
    }
    float bi[4] = {bi0, bi1, bi2, bi3};
    #pragma unroll
    for (int rg = 0; rg < 4; ++rg) {
      float b = bi[rg];
      b += __shfl_xor(b, 1);
      b += __shfl_xor(b, 2);
      b += __shfl_xor(b, 4);
      b += __shfl_xor(b, 8);
      bi[rg] = b;
    }
    // final softmax over k: bi pre-scaled by LOG2E -> exp2 direct
    const float eb0 = exp2_fast(bi[0]), eb1 = exp2_fast(bi[1]);
    const float eb2 = exp2_fast(bi[2]), eb3 = exp2_fast(bi[3]);
    float sb = eb0 + eb1 + eb2 + eb3;
    sb += __shfl_xor(sb, 16);
    const float rsb = __builtin_amdgcn_rcpf(sb);
    if (row < 4) {
      const float vsel = row == 0 ? eb0 : row == 1 ? eb1 : row == 2 ? eb2 : eb3;
      out[gid*16 + quad*4 + row] = vsel * rsb;
    }
    // rotate staged operands
    if (g < 3) {
      #pragma unroll
      for (int rg = 0; rg < 4; ++rg) msc[rg] = msn[rg];
      #pragma unroll
      for (int kt = 0; kt < 4; ++kt) { kfc[kt] = kfn[kt]; qpc[kt] = qpn[kt]; }
    }
  }
}

// ============================================================
extern "C" void kernel_launch(void* const* d_in, const int* in_sizes, int n_in,
                              void* d_out, int out_size, void* d_ws, size_t ws_size,
                              hipStream_t stream)
{
  const float* sp_fea  = (const float*)d_in[0];
  const float* sp_xyz  = (const float*)d_in[1];
  const float* o_p_fea = (const float*)d_in[2];
  // d_in[3] p_xyz unused by reference
  const float* Wq    = (const float*)d_in[4];
  const float* bq    = (const float*)d_in[5];
  const float* Wk    = (const float*)d_in[6];
  const float* bk    = (const float*)d_in[7];
  const float* Wv    = (const float*)d_in[8];
  const float* bv    = (const float*)d_in[9];
  const float* Wp1   = (const float*)d_in[10];
  const float* bp1   = (const float*)d_in[11];
  const float* gp    = (const float*)d_in[12];
  const float* betap = (const float*)d_in[13];
  const float* mp    = (const float*)d_in[14];
  const float* vp    = (const float*)d_in[15];
  const float* Wp2   = (const float*)d_in[16];
  const float* bp2   = (const float*)d_in[17];
  const float* g1    = (const float*)d_in[18];
  const float* beta1 = (const float*)d_in[19];
  const float* m1    = (const float*)d_in[20];
  const float* v1    = (const float*)d_in[21];
  const float* W1    = (const float*)d_in[22];
  const float* b1    = (const float*)d_in[23];
  const float* g2    = (const float*)d_in[24];
  const float* beta2 = (const float*)d_in[25];
  const float* m2    = (const float*)d_in[26];
  const float* v2    = (const float*)d_in[27];
  const float* W2    = (const float*)d_in[28];
  const float* b2    = (const float*)d_in[29];
  const int* c2p_idx_abs = (const int*)d_in[30];
  // d_in[31..34] unused by reference

  char* ws = (char*)d_ws;
  float* out = (float*)d_out;

  hipLaunchKernelGGL(k_prep, dim3(1015), dim3(256), 0, stream,
                     sp_fea, sp_xyz, Wk, bk, Wv, bv, Wp1, bp1, gp, betap, mp, vp,
                     Wp2, bp2, g1, beta1, m1, v1, bq,
                     Wq, W1, W2, g2, v2, b1, m2, beta2, ws);
  hipLaunchKernelGGL(k_main, dim3(2500), dim3(256), 0, stream,
                     c2p_idx_abs, b2, o_p_fea, ws, out);
}

// Round 9
// 198.228 us; speedup vs baseline: 1.0408x; 1.0408x over previous
//
#include <hip/hip_runtime.h>
#include <stdint.h>

#define EPS 1e-5f
#define LOG2E 1.4426950408889634f

// ---------------- problem constants ----------------
#define NPTS 80000
#define CDIM 128
#define ODIM 64
#define KNBR 8
#define MSUP 1000

// ---------------- workspace layout (bytes) ----------------
#define KP2H_OFF 0                 // [1000][128] f16 = 256 KB (BN1-folded k+pe table)
#define UT_OFF   (256*1024)        // [1000][64]  f32  = 256 KB (LOG2E-scaled, INTERLEAVED)
#define WQF_OFF  (512*1024)        // 32 frags * 1KB = 32 KB (Wq*s1c, A-layout, f16)
#define W1F_OFF  (544*1024)        // 16 frags * 1KB = 16 KB (W1*s2c, A-layout, f16)
#define W2F_OFF  (560*1024)        // 8 frags * 1KB  = 8 KB  (W2*LOG2E, B-layout, f16)
#define C1_OFF   (568*1024)        // [64] f32 ((b1-m2)*s2c + beta2)
#define WSTAGE_BYTES (16*1024 + 8*1024 + 256)   // 24832 (W1F..C1 contiguous blob)

typedef float f32x4 __attribute__((ext_vector_type(4)));
typedef _Float16 f16x8 __attribute__((ext_vector_type(8)));
typedef _Float16 f16x4 __attribute__((ext_vector_type(4)));
typedef _Float16 f16x2 __attribute__((ext_vector_type(2)));

union FragU { f16x8 v; unsigned u[4]; uint4 q; };

// f32 pair -> packed f16 (1 op: v_cvt_pkrtz_f16_f32)
__device__ inline unsigned pk_f16(float lo, float hi) {
#if __has_builtin(__builtin_amdgcn_cvt_pkrtz)
  return __builtin_bit_cast(unsigned, __builtin_amdgcn_cvt_pkrtz(lo, hi));
#else
  f16x2 h;
  h[0] = (_Float16)lo;
  h[1] = (_Float16)hi;
  return __builtin_bit_cast(unsigned, h);
#endif
}

__device__ inline float exp2_fast(float x) {
#if __has_builtin(__builtin_amdgcn_exp2f)
  return __builtin_amdgcn_exp2f(x);
#else
  return exp2f(x);
#endif
}

// ============================================================
// Kernel 1 (prep): blocks 0..999 per-superpoint tables; 1000..1014 weight swizzle.
// ALL MFMA operand tables now f16 (not bf16): gfx950 has packed f16 VALU
// (v_pk_add_f16/v_pk_max_f16) but NO packed bf16 VALU -- the bf16
// relu(k-q) in k_main scalarized through f32 and dominated VALUBusy (51%).
// mfma_f32_16x16x32_f16 runs at the same rate as bf16. f16 mantissa (11b)
// beats bf16 (8b) at these O(1..100) magnitudes; range is not a concern.
// ============================================================
__global__ __launch_bounds__(256)
void k_prep(const float* __restrict__ sp_fea, const float* __restrict__ sp_xyz,
            const float* __restrict__ Wk, const float* __restrict__ bk,
            const float* __restrict__ Wv, const float* __restrict__ bv,
            const float* __restrict__ Wp1, const float* __restrict__ bp1,
            const float* __restrict__ gp, const float* __restrict__ betap,
            const float* __restrict__ mp, const float* __restrict__ vp,
            const float* __restrict__ Wp2, const float* __restrict__ bp2,
            const float* __restrict__ g1, const float* __restrict__ beta1,
            const float* __restrict__ m1, const float* __restrict__ v1,
            const float* __restrict__ bq,
            const float* __restrict__ Wq, const float* __restrict__ W1,
            const float* __restrict__ W2,
            const float* __restrict__ g2, const float* __restrict__ v2,
            const float* __restrict__ b1, const float* __restrict__ m2,
            const float* __restrict__ beta2, char* __restrict__ ws)
{
  if (blockIdx.x < 1000) {
    unsigned short* kp2h = (unsigned short*)(ws + KP2H_OFF);
    float* uT = (float*)(ws + UT_OFF);
    const int m = blockIdx.x;
    const int t = threadIdx.x;
    const int c = t & 127, half = t >> 7;
    __shared__ float fea[128];
    __shared__ float pk[128], pv[128];
    if (t < 128) fea[t] = sp_fea[m * 128 + t];
    __syncthreads();
    float kv = 0.f, vv = 0.f;
    const float* wkc = Wk + half * 64 * 128 + c;
    const float* wvc = Wv + half * 64 * 128 + c;
    const float* feah = fea + half * 64;
    #pragma unroll 8
    for (int d = 0; d < 64; ++d) {
      const float f = feah[d];
      kv = fmaf(f, wkc[d * 128], kv);
      vv = fmaf(f, wvc[d * 128], vv);
    }
    if (half) { pk[c] = kv; pv[c] = vv; }
    __syncthreads();
    if (!half) {
      kv += pk[c] + bk[c];
      vv += pv[c] + bv[c];
      const float x0 = sp_xyz[m*3+0], x1 = sp_xyz[m*3+1], x2 = sp_xyz[m*3+2];
      float pe = bp2[c];
      #pragma unroll
      for (int ii = 0; ii < 3; ++ii) {
        float s = bp1[ii] + x0*Wp1[0*3+ii] + x1*Wp1[1*3+ii] + x2*Wp1[2*3+ii];
        s = (s - mp[ii]) * (gp[ii] * rsqrtf(vp[ii] + EPS)) + betap[ii];
        s = fmaxf(s, 0.0f);
        pe += s * Wp2[ii*128 + c];
      }
      const float s1c = g1[c] * rsqrtf(v1[c] + EPS);
      const float kpv = (kv + pe - m1[c] - bq[c]) * s1c + beta1[c];
      kp2h[m*128 + c] = (unsigned short)(pk_f16(kpv, kpv) & 0xFFFFu);
      pv[c] = vv + pe;          // reuse pv as (v+pe) storage
    }
    __syncthreads();
    // interleaved store: uTi[m][t] with t=row*4+nt holds u[m][row + nt*16]
    if (t < 64) {
      const int j = (t >> 2) + (t & 3) * 16;
      uT[m*64 + t] = (pv[j] + pv[j + 64]) * LOG2E;
    }
  } else {
    const int tid = (blockIdx.x - 1000) * 256 + threadIdx.x;
    if (tid < 2048) {
      // Wqf^T A-frags: frag f = kt*8+mt ; A[m=c][k=d], Wqf[d][c]=Wq[d][c]*s1c[c]
      const int e = tid, f = e >> 6, l = e & 63;
      const int kt = f >> 3, mt = f & 7;
      const int c = mt*16 + (l & 15);
      const int d0 = kt*32 + (l >> 4)*8;
      const float sc = g1[c] * rsqrtf(v1[c] + EPS);
      uint4 u;
      u.x = pk_f16(Wq[(d0+0)*128 + c]*sc, Wq[(d0+1)*128 + c]*sc);
      u.y = pk_f16(Wq[(d0+2)*128 + c]*sc, Wq[(d0+3)*128 + c]*sc);
      u.z = pk_f16(Wq[(d0+4)*128 + c]*sc, Wq[(d0+5)*128 + c]*sc);
      u.w = pk_f16(Wq[(d0+6)*128 + c]*sc, Wq[(d0+7)*128 + c]*sc);
      *(uint4*)(ws + WQF_OFF + e*16) = u;
    } else if (tid < 3072) {
      // W1f^T A-frags: frag f = kt*4+jt ; A[m=j][k=c], W1f[c][j]=W1[c][j]*s2c[j]
      const int e = tid - 2048, f = e >> 6, l = e & 63;
      const int kt = f >> 2, jt = f & 3;
      const int j = jt*16 + (l & 15);
      const int c0 = kt*32 + (l >> 4)*8;
      const float sc = g2[j] * rsqrtf(v2[j] + EPS);
      uint4 u;
      u.x = pk_f16(W1[(c0+0)*64 + j]*sc, W1[(c0+1)*64 + j]*sc);
      u.y = pk_f16(W1[(c0+2)*64 + j]*sc, W1[(c0+3)*64 + j]*sc);
      u.z = pk_f16(W1[(c0+4)*64 + j]*sc, W1[(c0+5)*64 + j]*sc);
      u.w = pk_f16(W1[(c0+6)*64 + j]*sc, W1[(c0+7)*64 + j]*sc);
      *(uint4*)(ws + W1F_OFF + e*16) = u;
    } else if (tid < 3584) {
      // W2 B-frags scaled by LOG2E: frag f = kt2*4+nt ; B[k=j][n=j']
      const int e = tid - 3072, f = e >> 6, l = e & 63;
      const int kt2 = f >> 2, nt = f & 3;
      const int jp = nt*16 + (l & 15);
      const int j0 = kt2*32 + (l >> 4)*8;
      uint4 u;
      u.x = pk_f16(W2[(j0+0)*64 + jp]*LOG2E, W2[(j0+1)*64 + jp]*LOG2E);
      u.y = pk_f16(W2[(j0+2)*64 + jp]*LOG2E, W2[(j0+3)*64 + jp]*LOG2E);
      u.z = pk_f16(W2[(j0+4)*64 + jp]*LOG2E, W2[(j0+5)*64 + jp]*LOG2E);
      u.w = pk_f16(W2[(j0+6)*64 + jp]*LOG2E, W2[(j0+7)*64 + jp]*LOG2E);
      *(uint4*)(ws + W2F_OFF + e*16) = u;
    } else if (tid < 3648) {
      const int j = tid - 3584;
      const float sc = g2[j] * rsqrtf(v2[j] + EPS);
      ((float*)(ws + C1_OFF))[j] = (b1[j] - m2[j]) * sc + beta2[j];
    }
  }
}

// ============================================================
// Kernel 2: fused main. Structure == R8 exactly (R1 addressing: pitch
// 272/144, C1 in LDS, no swizzles -- the only no-spill scheme, verified
// R2-R7) with the MFMA pipeline switched bf16 -> f16:
//   - relu(k-q): 4 v_pk_add_f16(neg) + 4 v_pk_max_f16 per kt, replacing
//     the ~36-op scalarized-bf16 f32 round trip  (VALU was 51% busy,
//     the serial X-compute chain was the floor at 28% occupancy)
//   - h2 relu-pack: cvt_pkrtz + v_pk_max_f16
//   - mfma_f32_16x16x32_f16 (same rate as bf16)
// f32 accumulators/softmax unchanged.
// ============================================================
#define H2_PITCH 144               // bytes/row (72 f16; 16B-aligned rows)
#define H2_SIZE  (16*144)          // 2304 B / wave
#define W1L_OFF  0
#define W2L_OFF  (16*1024)
#define C1L_OFF  (24*1024)
#define H2_BASE  24832
#define QL_OFF   (H2_BASE + 4*H2_SIZE)   // 34048 (16B aligned)
#define QL_PITCH 272                     // 256 B data + 16 B pad (16B aligned rows)
#define LDS_TOTAL (QL_OFF + 32*QL_PITCH) // 42752

__global__ __launch_bounds__(256, 3)
void k_main(const int* __restrict__ idx, const float* __restrict__ b2,
            const float* __restrict__ o_p_fea,
            const char* __restrict__ ws, float* __restrict__ out)
{
  const unsigned short* kp2h = (const unsigned short*)(ws + KP2H_OFF);
  const float* uT = (const float*)(ws + UT_OFF);

  __shared__ __align__(16) char lds[LDS_TOTAL];
  const int t = threadIdx.x;
  const int wave = t >> 6, l = t & 63;
  const int quad = l >> 4, row = l & 15;
  char* h2_w = lds + H2_BASE + wave * H2_SIZE;

  const int slot = blockIdx.x * 4 + wave;   // 0..9999 wave-slots
  const int gid0 = slot * 4;                // 4 group-tasks per wave
  const int nloc = row >> 3;

  // ---- stage weight fragments into block-shared LDS (24832 B) ----
  {
    const uint4* src = (const uint4*)(ws + W1F_OFF);
    uint4* dst = (uint4*)lds;
    #pragma unroll
    for (int i = 0; i < 7; ++i) {
      const int e = t + i * 256;
      if (e < WSTAGE_BYTES / 16) dst[e] = src[e];
    }
  }

  // ---- inline q-projection for this block's 32 points ----
  // wave w: tile = w>>1 (points blockbase + tile*16 .. +15), mts (w&1)*4..+3
  {
    const int tile = wave >> 1;
    const int mt0 = (wave & 1) * 4;
    const int nq = blockIdx.x * 32 + tile * 16 + row;
    const float* feab = o_p_fea + (size_t)nq * 128;
    f32x4 qa[4];
    #pragma unroll
    for (int mt = 0; mt < 4; ++mt) qa[mt] = (f32x4){0.f, 0.f, 0.f, 0.f};
    #pragma unroll
    for (int kt = 0; kt < 4; ++kt) {
      f32x4 fa = *(const f32x4*)(feab + kt*32 + quad*8);
      f32x4 fb = *(const f32x4*)(feab + kt*32 + quad*8 + 4);
      FragU bu;
      bu.u[0] = pk_f16(fa[0], fa[1]);
      bu.u[1] = pk_f16(fa[2], fa[3]);
      bu.u[2] = pk_f16(fb[0], fb[1]);
      bu.u[3] = pk_f16(fb[2], fb[3]);
      #pragma unroll
      for (int mt = 0; mt < 4; ++mt) {
        FragU wf;
        wf.q = *(const uint4*)(ws + WQF_OFF + (((kt*8 + mt0 + mt)*64 + l) * 16));
        qa[mt] = __builtin_amdgcn_mfma_f32_16x16x32_f16(wf.v, bu.v, qa[mt], 0, 0, 0);
      }
    }
    // D layout: n = l&15 (= row), c = (mt0+mt)*16 + quad*4 + reg -> linear-c row store
    char* lq = lds + QL_OFF + (tile*16 + row) * QL_PITCH;
    #pragma unroll
    for (int mt = 0; mt < 4; ++mt) {
      uint2 pp;
      pp.x = pk_f16(qa[mt][0], qa[mt][1]);
      pp.y = pk_f16(qa[mt][2], qa[mt][3]);
      *(uint2*)(lq + (mt0 + mt)*32 + quad*8) = pp;
    }
  }

  // prefetch this wave's 4 groups' gather indices (row pattern for kp2h)
  int mr4[4];
  #pragma unroll
  for (int g = 0; g < 4; ++g) mr4[g] = idx[(gid0 + g)*16 + row];

  __syncthreads();   // weights + q staged

  f32x4 c1r[4];
  #pragma unroll
  for (int jt = 0; jt < 4; ++jt)
    c1r[jt] = *(const f32x4*)(lds + C1L_OFF + (jt*16 + quad*4)*4);
  float b2r[4];
  #pragma unroll
  for (int nt = 0; nt < 4; ++nt) b2r[nt] = b2[row + nt*16] * LOG2E;

  // ---- group-0 staging: idx (quad pattern), kp2h row, q B-frags ----
  int msc[4];
  #pragma unroll
  for (int rg = 0; rg < 4; ++rg) msc[rg] = idx[gid0*16 + quad*4 + rg];
  uint4 kfc[4];
  {
    const uint4* kr = (const uint4*)(kp2h + (size_t)mr4[0] * 128);
    #pragma unroll
    for (int kt = 0; kt < 4; ++kt) kfc[kt] = kr[kt*4 + quad];
  }
  uint4 qpc[4];
  {
    const char* lqr = lds + QL_OFF + (wave*8 + nloc) * QL_PITCH;
    #pragma unroll
    for (int kt = 0; kt < 4; ++kt)
      qpc[kt] = *(const uint4*)(lqr + (kt*4 + quad)*16);
  }

  #pragma unroll 1
  for (int g = 0; g < 4; ++g) {
    const int gid = gid0 + g;
    // prefetch next group's operands (address-known; land during compute)
    int msn[4];
    uint4 kfn[4];
    if (g < 3) {
      #pragma unroll
      for (int rg = 0; rg < 4; ++rg) msn[rg] = idx[(gid+1)*16 + quad*4 + rg];
      const uint4* kr = (const uint4*)(kp2h + (size_t)mr4[g+1] * 128);
      #pragma unroll
      for (int kt = 0; kt < 4; ++kt) kfn[kt] = kr[kt*4 + quad];
    }

    // GEMM1 (transposed): h2^T = W1f^T @ X^T ; X = relu(kp2[m] - qs[n])
    // bias c1 folded in via MFMA C-in initialization
    f32x4 a1[4];
    #pragma unroll
    for (int jt = 0; jt < 4; ++jt) a1[jt] = c1r[jt];
    #pragma unroll
    for (int kt = 0; kt < 4; ++kt) {
      const f16x8 kv = __builtin_bit_cast(f16x8, kfc[kt]);
      const f16x8 qv = __builtin_bit_cast(f16x8, qpc[kt]);
      f16x8 z = {};
      f16x8 x = __builtin_elementwise_max((f16x8)(kv - qv), z);
      FragU xf;
      xf.v = x;
      #pragma unroll
      for (int jt = 0; jt < 4; ++jt) {
        const f16x8 wf = *(const f16x8*)(lds + W1L_OFF + (kt*4+jt)*1024 + l*16);
        a1[jt] = __builtin_amdgcn_mfma_f32_16x16x32_f16(wf, xf.v, a1[jt], 0, 0, 0);
      }
    }

    // pack + packed relu; D^T: n=row -> r, m=quad*4+reg+16*jt -> j
    #pragma unroll
    for (int jt = 0; jt < 4; ++jt) {
      uint2 pp;
      pp.x = pk_f16(a1[jt][0], a1[jt][1]);
      pp.y = pk_f16(a1[jt][2], a1[jt][3]);
      f16x4 h = __builtin_bit_cast(f16x4, pp);
      f16x4 z4 = {};
      h = __builtin_elementwise_max(h, z4);
      pp = __builtin_bit_cast(uint2, h);
      *(uint2*)(h2_w + row*H2_PITCH + (jt*16 + quad*4)*2) = pp;
    }

    // prefetch next group's q B-frags from LDS (qpc regs freed by GEMM1;
    // latency drains under GEMM2+softmax)
    uint4 qpn[4];
    if (g < 3) {
      const char* lqr = lds + QL_OFF + (wave*8 + (g+1)*2 + nloc) * QL_PITCH;
      #pragma unroll
      for (int kt = 0; kt < 4; ++kt)
        qpn[kt] = *(const uint4*)(lqr + (kt*4 + quad)*16);
    }

    // uT loads for THIS group (consumed in softmax; issued under GEMM2)
    f32x4 u4[4];
    #pragma unroll
    for (int rg = 0; rg < 4; ++rg)
      u4[rg] = *(const f32x4*)(uT + (size_t)msc[rg] * 64 + row * 4);

    // GEMM2: s2' = h2 @ (W2*LOG2E)
    f32x4 a2[4];
    #pragma unroll
    for (int nt = 0; nt < 4; ++nt) a2[nt] = (f32x4){0.f, 0.f, 0.f, 0.f};
    #pragma unroll
    for (int kt2 = 0; kt2 < 2; ++kt2) {
      const f16x8 af = *(const f16x8*)(h2_w + row*H2_PITCH + kt2*64 + quad*16);
      #pragma unroll
      for (int nt = 0; nt < 4; ++nt) {
        const f16x8 wf = *(const f16x8*)(lds + W2L_OFF + (kt2*4+nt)*1024 + l*16);
        a2[nt] = __builtin_amdgcn_mfma_f32_16x16x32_f16(af, wf, a2[nt], 0, 0, 0);
      }
    }
    // softmax over 8 rows/point + bi accumulation, fused per-nt
    float bi0 = 0.f, bi1 = 0.f, bi2 = 0.f, bi3 = 0.f;
    #pragma unroll
    for (int nt = 0; nt < 4; ++nt) {
      const float e0 = exp2_fast(a2[nt][0] + b2r[nt]);
      const float e1 = exp2_fast(a2[nt][1] + b2r[nt]);
      const float e2 = exp2_fast(a2[nt][2] + b2r[nt]);
      const float e3 = exp2_fast(a2[nt][3] + b2r[nt]);
      float s = e0 + e1 + e2 + e3;
      s += __shfl_xor(s, 16);
      const float rs = __builtin_amdgcn_rcpf(s);
      bi0 = fmaf(e0 * rs, u4[0][nt], bi0);
      bi1 = fmaf(e1 * rs, u4[1][nt], bi1);
      bi2 = fmaf(e2 * rs, u4[2][nt], bi2);
      bi3 = fmaf(e3 * rs, u4[3][nt], bi3);
    }
    float bi[4] = {bi0, bi1, bi2, bi3};
    #pragma unroll
    for (int rg = 0; rg < 4; ++rg) {
      float b = bi[rg];
      b += __shfl_xor(b, 1);
      b += __shfl_xor(b, 2);
      b += __shfl_xor(b, 4);
      b += __shfl_xor(b, 8);
      bi[rg] = b;
    }
    // final softmax over k: bi pre-scaled by LOG2E -> exp2 direct
    const float eb0 = exp2_fast(bi[0]), eb1 = exp2_fast(bi[1]);
    const float eb2 = exp2_fast(bi[2]), eb3 = exp2_fast(bi[3]);
    float sb = eb0 + eb1 + eb2 + eb3;
    sb += __shfl_xor(sb, 16);
    const float rsb = __builtin_amdgcn_rcpf(sb);
    if (row < 4) {
      const float vsel = row == 0 ? eb0 : row == 1 ? eb1 : row == 2 ? eb2 : eb3;
      out[gid*16 + quad*4 + row] = vsel * rsb;
    }
    // rotate staged operands
    if (g < 3) {
      #pragma unroll
      for (int rg = 0; rg < 4; ++rg) msc[rg] = msn[rg];
      #pragma unroll
      for (int kt = 0; kt < 4; ++kt) { kfc[kt] = kfn[kt]; qpc[kt] = qpn[kt]; }
    }
  }
}

// ============================================================
extern "C" void kernel_launch(void* const* d_in, const int* in_sizes, int n_in,
                              void* d_out, int out_size, void* d_ws, size_t ws_size,
                              hipStream_t stream)
{
  const float* sp_fea  = (const float*)d_in[0];
  const float* sp_xyz  = (const float*)d_in[1];
  const float* o_p_fea = (const float*)d_in[2];
  // d_in[3] p_xyz unused by reference
  const float* Wq    = (const float*)d_in[4];
  const float* bq    = (const float*)d_in[5];
  const float* Wk    = (const float*)d_in[6];
  const float* bk    = (const float*)d_in[7];
  const float* Wv    = (const float*)d_in[8];
  const float* bv    = (const float*)d_in[9];
  const float* Wp1   = (const float*)d_in[10];
  const float* bp1   = (const float*)d_in[11];
  const float* gp    = (const float*)d_in[12];
  const float* betap = (const float*)d_in[13];
  const float* mp    = (const float*)d_in[14];
  const float* vp    = (const float*)d_in[15];
  const float* Wp2   = (const float*)d_in[16];
  const float* bp2   = (const float*)d_in[17];
  const float* g1    = (const float*)d_in[18];
  const float* beta1 = (const float*)d_in[19];
  const float* m1    = (const float*)d_in[20];
  const float* v1    = (const float*)d_in[21];
  const float* W1    = (const float*)d_in[22];
  const float* b1    = (const float*)d_in[23];
  const float* g2    = (const float*)d_in[24];
  const float* beta2 = (const float*)d_in[25];
  const float* m2    = (const float*)d_in[26];
  const float* v2    = (const float*)d_in[27];
  const float* W2    = (const float*)d_in[28];
  const float* b2    = (const float*)d_in[29];
  const int* c2p_idx_abs = (const int*)d_in[30];
  // d_in[31..34] unused by reference

  char* ws = (char*)d_ws;
  float* out = (float*)d_out;

  hipLaunchKernelGGL(k_prep, dim3(1015), dim3(256), 0, stream,
                     sp_fea, sp_xyz, Wk, bk, Wv, bv, Wp1, bp1, gp, betap, mp, vp,
                     Wp2, bp2, g1, beta1, m1, v1, bq,
                     Wq, W1, W2, g2, v2, b1, m2, beta2, ws);
  hipLaunchKernelGGL(k_main, dim3(2500), dim3(256), 0, stream,
                     c2p_idx_abs, b2, o_p_fea, ws, out);
}

// Round 11
// 196.656 us; speedup vs baseline: 1.0491x; 1.0080x over previous
//
#include <hip/hip_runtime.h>
#include <stdint.h>

#define EPS 1e-5f
#define LOG2E 1.4426950408889634f

// ---------------- problem constants ----------------
#define NPTS 80000
#define CDIM 128
#define ODIM 64
#define KNBR 8
#define MSUP 1000

// ---------------- workspace layout (bytes) ----------------
#define KP2H_OFF 0                 // [1000][128] f16 = 256 KB (BN1-folded k+pe table)
#define UT_OFF   (256*1024)        // [1000][64]  f32  = 256 KB (LOG2E-scaled, INTERLEAVED)
#define WQF_OFF  (512*1024)        // 32 frags * 1KB = 32 KB (Wq*s1c, A-layout, f16)
#define W1F_OFF  (544*1024)        // 16 frags * 1KB = 16 KB (W1*s2c, A-layout, f16)
#define W2F_OFF  (560*1024)        // 8 frags * 1KB  = 8 KB  (W2*LOG2E, B-layout, f16)
#define C1_OFF   (568*1024)        // [64] f32 ((b1-m2)*s2c + beta2)
#define WSTAGE_BYTES (16*1024 + 8*1024 + 256)   // 24832 (W1F..C1 contiguous blob)

typedef float f32x4 __attribute__((ext_vector_type(4)));
typedef _Float16 f16x8 __attribute__((ext_vector_type(8)));
typedef _Float16 f16x4 __attribute__((ext_vector_type(4)));
typedef _Float16 f16x2 __attribute__((ext_vector_type(2)));

union FragU { f16x8 v; unsigned u[4]; uint4 q; };

// f32 pair -> packed f16 (1 op: v_cvt_pkrtz_f16_f32)
__device__ inline unsigned pk_f16(float lo, float hi) {
#if __has_builtin(__builtin_amdgcn_cvt_pkrtz)
  return __builtin_bit_cast(unsigned, __builtin_amdgcn_cvt_pkrtz(lo, hi));
#else
  f16x2 h;
  h[0] = (_Float16)lo;
  h[1] = (_Float16)hi;
  return __builtin_bit_cast(unsigned, h);
#endif
}

__device__ inline float exp2_fast(float x) {
#if __has_builtin(__builtin_amdgcn_exp2f)
  return __builtin_amdgcn_exp2f(x);
#else
  return exp2f(x);
#endif
}

// Sum across the 16-lane row, result broadcast to all 16 lanes.
// VALU DPP row_ror chain (v_add_f32_dpp) -- replaces 4 dependent
// ds_swizzle ops (DS pipe, ~30-60cy each) with 4 VALU ops (~4-8cy).
// Rotate-reduction is a valid all-lanes sum: after ror:8 lane i holds
// v[i]+v[i+8]; ror:4 -> 4-comb; ror:2 -> 8; ror:1 -> all 16.
// dpp_ctrl: row_ror:N = 0x120|N.
__device__ inline float row16_sum(float v) {
  float acc = v;
#if __has_builtin(__builtin_amdgcn_update_dpp)
  #define DPP_ADD(CTRL) {                                                     \
    int t_ = __builtin_amdgcn_update_dpp(0, __builtin_bit_cast(int, acc),     \
                                         (CTRL), 0xf, 0xf, true);             \
    acc += __builtin_bit_cast(float, t_); }
  DPP_ADD(0x128)  // row_ror:8
  DPP_ADD(0x124)  // row_ror:4
  DPP_ADD(0x122)  // row_ror:2
  DPP_ADD(0x121)  // row_ror:1
  #undef DPP_ADD
#else
  acc += __shfl_xor(acc, 8);
  acc += __shfl_xor(acc, 4);
  acc += __shfl_xor(acc, 2);
  acc += __shfl_xor(acc, 1);
#endif
  return acc;
}

// ============================================================
// Kernel 1 (prep): blocks 0..999 per-superpoint tables; 1000..1014 weight swizzle.
// f16 operand tables (R9): gfx950 has packed f16 VALU but no packed bf16.
// ============================================================
__global__ __launch_bounds__(256)
void k_prep(const float* __restrict__ sp_fea, const float* __restrict__ sp_xyz,
            const float* __restrict__ Wk, const float* __restrict__ bk,
            const float* __restrict__ Wv, const float* __restrict__ bv,
            const float* __restrict__ Wp1, const float* __restrict__ bp1,
            const float* __restrict__ gp, const float* __restrict__ betap,
            const float* __restrict__ mp, const float* __restrict__ vp,
            const float* __restrict__ Wp2, const float* __restrict__ bp2,
            const float* __restrict__ g1, const float* __restrict__ beta1,
            const float* __restrict__ m1, const float* __restrict__ v1,
            const float* __restrict__ bq,
            const float* __restrict__ Wq, const float* __restrict__ W1,
            const float* __restrict__ W2,
            const float* __restrict__ g2, const float* __restrict__ v2,
            const float* __restrict__ b1, const float* __restrict__ m2,
            const float* __restrict__ beta2, char* __restrict__ ws)
{
  if (blockIdx.x < 1000) {
    unsigned short* kp2h = (unsigned short*)(ws + KP2H_OFF);
    float* uT = (float*)(ws + UT_OFF);
    const int m = blockIdx.x;
    const int t = threadIdx.x;
    const int c = t & 127, half = t >> 7;
    __shared__ float fea[128];
    __shared__ float pk[128], pv[128];
    if (t < 128) fea[t] = sp_fea[m * 128 + t];
    __syncthreads();
    float kv = 0.f, vv = 0.f;
    const float* wkc = Wk + half * 64 * 128 + c;
    const float* wvc = Wv + half * 64 * 128 + c;
    const float* feah = fea + half * 64;
    #pragma unroll 8
    for (int d = 0; d < 64; ++d) {
      const float f = feah[d];
      kv = fmaf(f, wkc[d * 128], kv);
      vv = fmaf(f, wvc[d * 128], vv);
    }
    if (half) { pk[c] = kv; pv[c] = vv; }
    __syncthreads();
    if (!half) {
      kv += pk[c] + bk[c];
      vv += pv[c] + bv[c];
      const float x0 = sp_xyz[m*3+0], x1 = sp_xyz[m*3+1], x2 = sp_xyz[m*3+2];
      float pe = bp2[c];
      #pragma unroll
      for (int ii = 0; ii < 3; ++ii) {
        float s = bp1[ii] + x0*Wp1[0*3+ii] + x1*Wp1[1*3+ii] + x2*Wp1[2*3+ii];
        s = (s - mp[ii]) * (gp[ii] * rsqrtf(vp[ii] + EPS)) + betap[ii];
        s = fmaxf(s, 0.0f);
        pe += s * Wp2[ii*128 + c];
      }
      const float s1c = g1[c] * rsqrtf(v1[c] + EPS);
      const float kpv = (kv + pe - m1[c] - bq[c]) * s1c + beta1[c];
      kp2h[m*128 + c] = (unsigned short)(pk_f16(kpv, kpv) & 0xFFFFu);
      pv[c] = vv + pe;          // reuse pv as (v+pe) storage
    }
    __syncthreads();
    // interleaved store: uTi[m][t] with t=row*4+nt holds u[m][row + nt*16]
    if (t < 64) {
      const int j = (t >> 2) + (t & 3) * 16;
      uT[m*64 + t] = (pv[j] + pv[j + 64]) * LOG2E;
    }
  } else {
    const int tid = (blockIdx.x - 1000) * 256 + threadIdx.x;
    if (tid < 2048) {
      // Wqf^T A-frags: frag f = kt*8+mt ; A[m=c][k=d], Wqf[d][c]=Wq[d][c]*s1c[c]
      const int e = tid, f = e >> 6, l = e & 63;
      const int kt = f >> 3, mt = f & 7;
      const int c = mt*16 + (l & 15);
      const int d0 = kt*32 + (l >> 4)*8;
      const float sc = g1[c] * rsqrtf(v1[c] + EPS);
      uint4 u;
      u.x = pk_f16(Wq[(d0+0)*128 + c]*sc, Wq[(d0+1)*128 + c]*sc);
      u.y = pk_f16(Wq[(d0+2)*128 + c]*sc, Wq[(d0+3)*128 + c]*sc);
      u.z = pk_f16(Wq[(d0+4)*128 + c]*sc, Wq[(d0+5)*128 + c]*sc);
      u.w = pk_f16(Wq[(d0+6)*128 + c]*sc, Wq[(d0+7)*128 + c]*sc);
      *(uint4*)(ws + WQF_OFF + e*16) = u;
    } else if (tid < 3072) {
      // W1f^T A-frags: frag f = kt*4+jt ; A[m=j][k=c], W1f[c][j]=W1[c][j]*s2c[j]
      const int e = tid - 2048, f = e >> 6, l = e & 63;
      const int kt = f >> 2, jt = f & 3;
      const int j = jt*16 + (l & 15);
      const int c0 = kt*32 + (l >> 4)*8;
      const float sc = g2[j] * rsqrtf(v2[j] + EPS);
      uint4 u;
      u.x = pk_f16(W1[(c0+0)*64 + j]*sc, W1[(c0+1)*64 + j]*sc);
      u.y = pk_f16(W1[(c0+2)*64 + j]*sc, W1[(c0+3)*64 + j]*sc);
      u.z = pk_f16(W1[(c0+4)*64 + j]*sc, W1[(c0+5)*64 + j]*sc);
      u.w = pk_f16(W1[(c0+6)*64 + j]*sc, W1[(c0+7)*64 + j]*sc);
      *(uint4*)(ws + W1F_OFF + e*16) = u;
    } else if (tid < 3584) {
      // W2 B-frags scaled by LOG2E: frag f = kt2*4+nt ; B[k=j][n=j']
      const int e = tid - 3072, f = e >> 6, l = e & 63;
      const int kt2 = f >> 2, nt = f & 3;
      const int jp = nt*16 + (l & 15);
      const int j0 = kt2*32 + (l >> 4)*8;
      uint4 u;
      u.x = pk_f16(W2[(j0+0)*64 + jp]*LOG2E, W2[(j0+1)*64 + jp]*LOG2E);
      u.y = pk_f16(W2[(j0+2)*64 + jp]*LOG2E, W2[(j0+3)*64 + jp]*LOG2E);
      u.z = pk_f16(W2[(j0+4)*64 + jp]*LOG2E, W2[(j0+5)*64 + jp]*LOG2E);
      u.w = pk_f16(W2[(j0+6)*64 + jp]*LOG2E, W2[(j0+7)*64 + jp]*LOG2E);
      *(uint4*)(ws + W2F_OFF + e*16) = u;
    } else if (tid < 3648) {
      const int j = tid - 3584;
      const float sc = g2[j] * rsqrtf(v2[j] + EPS);
      ((float*)(ws + C1_OFF))[j] = (b1[j] - m2[j]) * sc + beta2[j];
    }
  }
}

// ============================================================
// Kernel 2: fused main. Structure == R9 (f16 MFMA pipeline, R1
// no-spill addressing: pitch 272/144, C1 in LDS) + ONE change:
// the bi-reduction (sum over 16-lane row) moved from 16 ds_swizzle
// (DS pipe, dominant per-group latency chain: ~47 DS ops/group at
// 2.2 waves/SIMD -> DS-pipe-bound) to VALU DPP row_ror chains.
// ============================================================
#define H2_PITCH 144               // bytes/row (72 f16; 16B-aligned rows)
#define H2_SIZE  (16*144)          // 2304 B / wave
#define W1L_OFF  0
#define W2L_OFF  (16*1024)
#define C1L_OFF  (24*1024)
#define H2_BASE  24832
#define QL_OFF   (H2_BASE + 4*H2_SIZE)   // 34048 (16B aligned)
#define QL_PITCH 272                     // 256 B data + 16 B pad (16B aligned rows)
#define LDS_TOTAL (QL_OFF + 32*QL_PITCH) // 42752

__global__ __launch_bounds__(256, 3)
void k_main(const int* __restrict__ idx, const float* __restrict__ b2,
            const float* __restrict__ o_p_fea,
            const char* __restrict__ ws, float* __restrict__ out)
{
  const unsigned short* kp2h = (const unsigned short*)(ws + KP2H_OFF);
  const float* uT = (const float*)(ws + UT_OFF);

  __shared__ __align__(16) char lds[LDS_TOTAL];
  const int t = threadIdx.x;
  const int wave = t >> 6, l = t & 63;
  const int quad = l >> 4, row = l & 15;
  char* h2_w = lds + H2_BASE + wave * H2_SIZE;

  const int slot = blockIdx.x * 4 + wave;   // 0..9999 wave-slots
  const int gid0 = slot * 4;                // 4 group-tasks per wave
  const int nloc = row >> 3;

  // ---- stage weight fragments into block-shared LDS (24832 B) ----
  {
    const uint4* src = (const uint4*)(ws + W1F_OFF);
    uint4* dst = (uint4*)lds;
    #pragma unroll
    for (int i = 0; i < 7; ++i) {
      const int e = t + i * 256;
      if (e < WSTAGE_BYTES / 16) dst[e] = src[e];
    }
  }

  // ---- inline q-projection for this block's 32 points ----
  // wave w: tile = w>>1 (points blockbase + tile*16 .. +15), mts (w&1)*4..+3
  {
    const int tile = wave >> 1;
    const int mt0 = (wave & 1) * 4;
    const int nq = blockIdx.x * 32 + tile * 16 + row;
    const float* feab = o_p_fea + (size_t)nq * 128;
    f32x4 qa[4];
    #pragma unroll
    for (int mt = 0; mt < 4; ++mt) qa[mt] = (f32x4){0.f, 0.f, 0.f, 0.f};
    #pragma unroll
    for (int kt = 0; kt < 4; ++kt) {
      f32x4 fa = *(const f32x4*)(feab + kt*32 + quad*8);
      f32x4 fb = *(const f32x4*)(feab + kt*32 + quad*8 + 4);
      FragU bu;
      bu.u[0] = pk_f16(fa[0], fa[1]);
      bu.u[1] = pk_f16(fa[2], fa[3]);
      bu.u[2] = pk_f16(fb[0], fb[1]);
      bu.u[3] = pk_f16(fb[2], fb[3]);
      #pragma unroll
      for (int mt = 0; mt < 4; ++mt) {
        FragU wf;
        wf.q = *(const uint4*)(ws + WQF_OFF + (((kt*8 + mt0 + mt)*64 + l) * 16));
        qa[mt] = __builtin_amdgcn_mfma_f32_16x16x32_f16(wf.v, bu.v, qa[mt], 0, 0, 0);
      }
    }
    // D layout: n = l&15 (= row), c = (mt0+mt)*16 + quad*4 + reg -> linear-c row store
    char* lq = lds + QL_OFF + (tile*16 + row) * QL_PITCH;
    #pragma unroll
    for (int mt = 0; mt < 4; ++mt) {
      uint2 pp;
      pp.x = pk_f16(qa[mt][0], qa[mt][1]);
      pp.y = pk_f16(qa[mt][2], qa[mt][3]);
      *(uint2*)(lq + (mt0 + mt)*32 + quad*8) = pp;
    }
  }

  // prefetch this wave's 4 groups' gather indices (row pattern for kp2h)
  int mr4[4];
  #pragma unroll
  for (int g = 0; g < 4; ++g) mr4[g] = idx[(gid0 + g)*16 + row];

  __syncthreads();   // weights + q staged

  f32x4 c1r[4];
  #pragma unroll
  for (int jt = 0; jt < 4; ++jt)
    c1r[jt] = *(const f32x4*)(lds + C1L_OFF + (jt*16 + quad*4)*4);
  float b2r[4];
  #pragma unroll
  for (int nt = 0; nt < 4; ++nt) b2r[nt] = b2[row + nt*16] * LOG2E;

  // ---- group-0 staging: idx (quad pattern), kp2h row, q B-frags ----
  int msc[4];
  #pragma unroll
  for (int rg = 0; rg < 4; ++rg) msc[rg] = idx[gid0*16 + quad*4 + rg];
  uint4 kfc[4];
  {
    const uint4* kr = (const uint4*)(kp2h + (size_t)mr4[0] * 128);
    #pragma unroll
    for (int kt = 0; kt < 4; ++kt) kfc[kt] = kr[kt*4 + quad];
  }
  uint4 qpc[4];
  {
    const char* lqr = lds + QL_OFF + (wave*8 + nloc) * QL_PITCH;
    #pragma unroll
    for (int kt = 0; kt < 4; ++kt)
      qpc[kt] = *(const uint4*)(lqr + (kt*4 + quad)*16);
  }

  #pragma unroll 1
  for (int g = 0; g < 4; ++g) {
    const int gid = gid0 + g;
    // prefetch next group's operands (address-known; land during compute)
    int msn[4];
    uint4 kfn[4];
    if (g < 3) {
      #pragma unroll
      for (int rg = 0; rg < 4; ++rg) msn[rg] = idx[(gid+1)*16 + quad*4 + rg];
      const uint4* kr = (const uint4*)(kp2h + (size_t)mr4[g+1] * 128);
      #pragma unroll
      for (int kt = 0; kt < 4; ++kt) kfn[kt] = kr[kt*4 + quad];
    }

    // GEMM1 (transposed): h2^T = W1f^T @ X^T ; X = relu(kp2[m] - qs[n])
    // bias c1 folded in via MFMA C-in initialization
    f32x4 a1[4];
    #pragma unroll
    for (int jt = 0; jt < 4; ++jt) a1[jt] = c1r[jt];
    #pragma unroll
    for (int kt = 0; kt < 4; ++kt) {
      const f16x8 kv = __builtin_bit_cast(f16x8, kfc[kt]);
      const f16x8 qv = __builtin_bit_cast(f16x8, qpc[kt]);
      f16x8 z = {};
      f16x8 x = __builtin_elementwise_max((f16x8)(kv - qv), z);
      FragU xf;
      xf.v = x;
      #pragma unroll
      for (int jt = 0; jt < 4; ++jt) {
        const f16x8 wf = *(const f16x8*)(lds + W1L_OFF + (kt*4+jt)*1024 + l*16);
        a1[jt] = __builtin_amdgcn_mfma_f32_16x16x32_f16(wf, xf.v, a1[jt], 0, 0, 0);
      }
    }

    // pack + packed relu; D^T: n=row -> r, m=quad*4+reg+16*jt -> j
    #pragma unroll
    for (int jt = 0; jt < 4; ++jt) {
      uint2 pp;
      pp.x = pk_f16(a1[jt][0], a1[jt][1]);
      pp.y = pk_f16(a1[jt][2], a1[jt][3]);
      f16x4 h = __builtin_bit_cast(f16x4, pp);
      f16x4 z4 = {};
      h = __builtin_elementwise_max(h, z4);
      pp = __builtin_bit_cast(uint2, h);
      *(uint2*)(h2_w + row*H2_PITCH + (jt*16 + quad*4)*2) = pp;
    }

    // prefetch next group's q B-frags from LDS (qpc regs freed by GEMM1;
    // latency drains under GEMM2+softmax)
    uint4 qpn[4];
    if (g < 3) {
      const char* lqr = lds + QL_OFF + (wave*8 + (g+1)*2 + nloc) * QL_PITCH;
      #pragma unroll
      for (int kt = 0; kt < 4; ++kt)
        qpn[kt] = *(const uint4*)(lqr + (kt*4 + quad)*16);
    }

    // uT loads for THIS group (consumed in softmax; issued under GEMM2)
    f32x4 u4[4];
    #pragma unroll
    for (int rg = 0; rg < 4; ++rg)
      u4[rg] = *(const f32x4*)(uT + (size_t)msc[rg] * 64 + row * 4);

    // GEMM2: s2' = h2 @ (W2*LOG2E)
    f32x4 a2[4];
    #pragma unroll
    for (int nt = 0; nt < 4; ++nt) a2[nt] = (f32x4){0.f, 0.f, 0.f, 0.f};
    #pragma unroll
    for (int kt2 = 0; kt2 < 2; ++kt2) {
      const f16x8 af = *(const f16x8*)(h2_w + row*H2_PITCH + kt2*64 + quad*16);
      #pragma unroll
      for (int nt = 0; nt < 4; ++nt) {
        const f16x8 wf = *(const f16x8*)(lds + W2L_OFF + (kt2*4+nt)*1024 + l*16);
        a2[nt] = __builtin_amdgcn_mfma_f32_16x16x32_f16(af, wf, a2[nt], 0, 0, 0);
      }
    }
    // softmax over 8 rows/point + bi accumulation, fused per-nt
    float bi0 = 0.f, bi1 = 0.f, bi2 = 0.f, bi3 = 0.f;
    #pragma unroll
    for (int nt = 0; nt < 4; ++nt) {
      const float e0 = exp2_fast(a2[nt][0] + b2r[nt]);
      const float e1 = exp2_fast(a2[nt][1] + b2r[nt]);
      const float e2 = exp2_fast(a2[nt][2] + b2r[nt]);
      const float e3 = exp2_fast(a2[nt][3] + b2r[nt]);
      float s = e0 + e1 + e2 + e3;
      s += __shfl_xor(s, 16);
      const float rs = __builtin_amdgcn_rcpf(s);
      bi0 = fmaf(e0 * rs, u4[0][nt], bi0);
      bi1 = fmaf(e1 * rs, u4[1][nt], bi1);
      bi2 = fmaf(e2 * rs, u4[2][nt], bi2);
      bi3 = fmaf(e3 * rs, u4[3][nt], bi3);
    }
    // 16-lane row reduction via VALU DPP (was 16 ds_swizzle)
    float bi[4];
    bi[0] = row16_sum(bi0);
    bi[1] = row16_sum(bi1);
    bi[2] = row16_sum(bi2);
    bi[3] = row16_sum(bi3);
    // final softmax over k: bi pre-scaled by LOG2E -> exp2 direct
    const float eb0 = exp2_fast(bi[0]), eb1 = exp2_fast(bi[1]);
    const float eb2 = exp2_fast(bi[2]), eb3 = exp2_fast(bi[3]);
    float sb = eb0 + eb1 + eb2 + eb3;
    sb += __shfl_xor(sb, 16);
    const float rsb = __builtin_amdgcn_rcpf(sb);
    if (row < 4) {
      const float vsel = row == 0 ? eb0 : row == 1 ? eb1 : row == 2 ? eb2 : eb3;
      out[gid*16 + quad*4 + row] = vsel * rsb;
    }
    // rotate staged operands
    if (g < 3) {
      #pragma unroll
      for (int rg = 0; rg < 4; ++rg) msc[rg] = msn[rg];
      #pragma unroll
      for (int kt = 0; kt < 4; ++kt) { kfc[kt] = kfn[kt]; qpc[kt] = qpn[kt]; }
    }
  }
}

// ============================================================
extern "C" void kernel_launch(void* const* d_in, const int* in_sizes, int n_in,
                              void* d_out, int out_size, void* d_ws, size_t ws_size,
                              hipStream_t stream)
{
  const float* sp_fea  = (const float*)d_in[0];
  const float* sp_xyz  = (const float*)d_in[1];
  const float* o_p_fea = (const float*)d_in[2];
  // d_in[3] p_xyz unused by reference
  const float* Wq    = (const float*)d_in[4];
  const float* bq    = (const float*)d_in[5];
  const float* Wk    = (const float*)d_in[6];
  const float* bk    = (const float*)d_in[7];
  const float* Wv    = (const float*)d_in[8];
  const float* bv    = (const float*)d_in[9];
  const float* Wp1   = (const float*)d_in[10];
  const float* bp1   = (const float*)d_in[11];
  const float* gp    = (const float*)d_in[12];
  const float* betap = (const float*)d_in[13];
  const float* mp    = (const float*)d_in[14];
  const float* vp    = (const float*)d_in[15];
  const float* Wp2   = (const float*)d_in[16];
  const float* bp2   = (const float*)d_in[17];
  const float* g1    = (const float*)d_in[18];
  const float* beta1 = (const float*)d_in[19];
  const float* m1    = (const float*)d_in[20];
  const float* v1    = (const float*)d_in[21];
  const float* W1    = (const float*)d_in[22];
  const float* b1    = (const float*)d_in[23];
  const float* g2    = (const float*)d_in[24];
  const float* beta2 = (const float*)d_in[25];
  const float* m2    = (const float*)d_in[26];
  const float* v2    = (const float*)d_in[27];
  const float* W2    = (const float*)d_in[28];
  const float* b2    = (const float*)d_in[29];
  const int* c2p_idx_abs = (const int*)d_in[30];
  // d_in[31..34] unused by reference

  char* ws = (char*)d_ws;
  float* out = (float*)d_out;

  hipLaunchKernelGGL(k_prep, dim3(1015), dim3(256), 0, stream,
                     sp_fea, sp_xyz, Wk, bk, Wv, bv, Wp1, bp1, gp, betap, mp, vp,
                     Wp2, bp2, g1, beta1, m1, v1, bq,
                     Wq, W1, W2, g2, v2, b1, m2, beta2, ws);
  hipLaunchKernelGGL(k_main, dim3(2500), dim3(256), 0, stream,
                     c2p_idx_abs, b2, o_p_fea, ws, out);
}

// Round 12
// 194.440 us; speedup vs baseline: 1.0611x; 1.0114x over previous
//
#include <hip/hip_runtime.h>
#include <stdint.h>

#define EPS 1e-5f
#define LOG2E 1.4426950408889634f

// ---------------- problem constants ----------------
#define NPTS 80000
#define CDIM 128
#define ODIM 64
#define KNBR 8
#define MSUP 1000

// ---------------- workspace layout (bytes) ----------------
#define KP2H_OFF 0                 // [1000][128] f16 = 256 KB (BN1-folded k+pe table)
#define UT_OFF   (256*1024)        // [1000][64]  f32  = 256 KB (LOG2E-scaled, INTERLEAVED)
#define WQF_OFF  (512*1024)        // 32 frags * 1KB = 32 KB (Wq*s1c, A-layout, f16)
#define W1F_OFF  (544*1024)        // 16 frags * 1KB = 16 KB (W1*s2c, A-layout, f16)
#define W2F_OFF  (560*1024)        // 8 frags * 1KB  = 8 KB  (W2*LOG2E, B-layout, f16)
#define C1_OFF   (568*1024)        // [64] f32 ((b1-m2)*s2c + beta2)
#define WSTAGE_BYTES (16*1024 + 8*1024 + 256)   // 24832 (W1F..C1 contiguous blob)

typedef float f32x4 __attribute__((ext_vector_type(4)));
typedef _Float16 f16x8 __attribute__((ext_vector_type(8)));
typedef _Float16 f16x4 __attribute__((ext_vector_type(4)));
typedef _Float16 f16x2 __attribute__((ext_vector_type(2)));

union FragU { f16x8 v; unsigned u[4]; uint4 q; };

// f32 pair -> packed f16 (1 op: v_cvt_pkrtz_f16_f32)
__device__ inline unsigned pk_f16(float lo, float hi) {
#if __has_builtin(__builtin_amdgcn_cvt_pkrtz)
  return __builtin_bit_cast(unsigned, __builtin_amdgcn_cvt_pkrtz(lo, hi));
#else
  f16x2 h;
  h[0] = (_Float16)lo;
  h[1] = (_Float16)hi;
  return __builtin_bit_cast(unsigned, h);
#endif
}

__device__ inline float exp2_fast(float x) {
#if __has_builtin(__builtin_amdgcn_exp2f)
  return __builtin_amdgcn_exp2f(x);
#else
  return exp2f(x);
#endif
}

// Sum across the 16-lane row, broadcast to all 16 lanes (VALU DPP row_ror).
__device__ inline float row16_sum(float v) {
  float acc = v;
#if __has_builtin(__builtin_amdgcn_update_dpp)
  #define DPP_ADD(CTRL) {                                                     \
    int t_ = __builtin_amdgcn_update_dpp(0, __builtin_bit_cast(int, acc),     \
                                         (CTRL), 0xf, 0xf, true);             \
    acc += __builtin_bit_cast(float, t_); }
  DPP_ADD(0x128)  // row_ror:8
  DPP_ADD(0x124)  // row_ror:4
  DPP_ADD(0x122)  // row_ror:2
  DPP_ADD(0x121)  // row_ror:1
  #undef DPP_ADD
#else
  acc += __shfl_xor(acc, 8);
  acc += __shfl_xor(acc, 4);
  acc += __shfl_xor(acc, 2);
  acc += __shfl_xor(acc, 1);
#endif
  return acc;
}

// ============================================================
// Kernel 1 (prep): blocks 0..999 per-superpoint tables; 1000..1014 weight swizzle.
// f16 operand tables (R9): gfx950 has packed f16 VALU but no packed bf16.
// ============================================================
__global__ __launch_bounds__(256)
void k_prep(const float* __restrict__ sp_fea, const float* __restrict__ sp_xyz,
            const float* __restrict__ Wk, const float* __restrict__ bk,
            const float* __restrict__ Wv, const float* __restrict__ bv,
            const float* __restrict__ Wp1, const float* __restrict__ bp1,
            const float* __restrict__ gp, const float* __restrict__ betap,
            const float* __restrict__ mp, const float* __restrict__ vp,
            const float* __restrict__ Wp2, const float* __restrict__ bp2,
            const float* __restrict__ g1, const float* __restrict__ beta1,
            const float* __restrict__ m1, const float* __restrict__ v1,
            const float* __restrict__ bq,
            const float* __restrict__ Wq, const float* __restrict__ W1,
            const float* __restrict__ W2,
            const float* __restrict__ g2, const float* __restrict__ v2,
            const float* __restrict__ b1, const float* __restrict__ m2,
            const float* __restrict__ beta2, char* __restrict__ ws)
{
  if (blockIdx.x < 1000) {
    unsigned short* kp2h = (unsigned short*)(ws + KP2H_OFF);
    float* uT = (float*)(ws + UT_OFF);
    const int m = blockIdx.x;
    const int t = threadIdx.x;
    const int c = t & 127, half = t >> 7;
    __shared__ float fea[128];
    __shared__ float pk[128], pv[128];
    if (t < 128) fea[t] = sp_fea[m * 128 + t];
    __syncthreads();
    float kv = 0.f, vv = 0.f;
    const float* wkc = Wk + half * 64 * 128 + c;
    const float* wvc = Wv + half * 64 * 128 + c;
    const float* feah = fea + half * 64;
    #pragma unroll 8
    for (int d = 0; d < 64; ++d) {
      const float f = feah[d];
      kv = fmaf(f, wkc[d * 128], kv);
      vv = fmaf(f, wvc[d * 128], vv);
    }
    if (half) { pk[c] = kv; pv[c] = vv; }
    __syncthreads();
    if (!half) {
      kv += pk[c] + bk[c];
      vv += pv[c] + bv[c];
      const float x0 = sp_xyz[m*3+0], x1 = sp_xyz[m*3+1], x2 = sp_xyz[m*3+2];
      float pe = bp2[c];
      #pragma unroll
      for (int ii = 0; ii < 3; ++ii) {
        float s = bp1[ii] + x0*Wp1[0*3+ii] + x1*Wp1[1*3+ii] + x2*Wp1[2*3+ii];
        s = (s - mp[ii]) * (gp[ii] * rsqrtf(vp[ii] + EPS)) + betap[ii];
        s = fmaxf(s, 0.0f);
        pe += s * Wp2[ii*128 + c];
      }
      const float s1c = g1[c] * rsqrtf(v1[c] + EPS);
      const float kpv = (kv + pe - m1[c] - bq[c]) * s1c + beta1[c];
      kp2h[m*128 + c] = (unsigned short)(pk_f16(kpv, kpv) & 0xFFFFu);
      pv[c] = vv + pe;          // reuse pv as (v+pe) storage
    }
    __syncthreads();
    // interleaved store: uTi[m][t] with t=row*4+nt holds u[m][row + nt*16]
    if (t < 64) {
      const int j = (t >> 2) + (t & 3) * 16;
      uT[m*64 + t] = (pv[j] + pv[j + 64]) * LOG2E;
    }
  } else {
    const int tid = (blockIdx.x - 1000) * 256 + threadIdx.x;
    if (tid < 2048) {
      // Wqf^T A-frags: frag f = kt*8+mt ; A[m=c][k=d], Wqf[d][c]=Wq[d][c]*s1c[c]
      const int e = tid, f = e >> 6, l = e & 63;
      const int kt = f >> 3, mt = f & 7;
      const int c = mt*16 + (l & 15);
      const int d0 = kt*32 + (l >> 4)*8;
      const float sc = g1[c] * rsqrtf(v1[c] + EPS);
      uint4 u;
      u.x = pk_f16(Wq[(d0+0)*128 + c]*sc, Wq[(d0+1)*128 + c]*sc);
      u.y = pk_f16(Wq[(d0+2)*128 + c]*sc, Wq[(d0+3)*128 + c]*sc);
      u.z = pk_f16(Wq[(d0+4)*128 + c]*sc, Wq[(d0+5)*128 + c]*sc);
      u.w = pk_f16(Wq[(d0+6)*128 + c]*sc, Wq[(d0+7)*128 + c]*sc);
      *(uint4*)(ws + WQF_OFF + e*16) = u;
    } else if (tid < 3072) {
      // W1f^T A-frags: frag f = kt*4+jt ; A[m=j][k=c], W1f[c][j]=W1[c][j]*s2c[j]
      const int e = tid - 2048, f = e >> 6, l = e & 63;
      const int kt = f >> 2, jt = f & 3;
      const int j = jt*16 + (l & 15);
      const int c0 = kt*32 + (l >> 4)*8;
      const float sc = g2[j] * rsqrtf(v2[j] + EPS);
      uint4 u;
      u.x = pk_f16(W1[(c0+0)*64 + j]*sc, W1[(c0+1)*64 + j]*sc);
      u.y = pk_f16(W1[(c0+2)*64 + j]*sc, W1[(c0+3)*64 + j]*sc);
      u.z = pk_f16(W1[(c0+4)*64 + j]*sc, W1[(c0+5)*64 + j]*sc);
      u.w = pk_f16(W1[(c0+6)*64 + j]*sc, W1[(c0+7)*64 + j]*sc);
      *(uint4*)(ws + W1F_OFF + e*16) = u;
    } else if (tid < 3584) {
      // W2 B-frags scaled by LOG2E: frag f = kt2*4+nt ; B[k=j][n=j']
      const int e = tid - 3072, f = e >> 6, l = e & 63;
      const int kt2 = f >> 2, nt = f & 3;
      const int jp = nt*16 + (l & 15);
      const int j0 = kt2*32 + (l >> 4)*8;
      uint4 u;
      u.x = pk_f16(W2[(j0+0)*64 + jp]*LOG2E, W2[(j0+1)*64 + jp]*LOG2E);
      u.y = pk_f16(W2[(j0+2)*64 + jp]*LOG2E, W2[(j0+3)*64 + jp]*LOG2E);
      u.z = pk_f16(W2[(j0+4)*64 + jp]*LOG2E, W2[(j0+5)*64 + jp]*LOG2E);
      u.w = pk_f16(W2[(j0+6)*64 + jp]*LOG2E, W2[(j0+7)*64 + jp]*LOG2E);
      *(uint4*)(ws + W2F_OFF + e*16) = u;
    } else if (tid < 3648) {
      const int j = tid - 3584;
      const float sc = g2[j] * rsqrtf(v2[j] + EPS);
      ((float*)(ws + C1_OFF))[j] = (b1[j] - m2[j]) * sc + beta2[j];
    }
  }
}

// ============================================================
// Kernel 2: fused main. R11 (f16 pipeline + DPP reduce, no-spill R1
// addressing) + SOFTWARE PIPELINE: double-buffered h2, loop body =
// {GEMM2(g)+softmax+store  ||  GEMM1(g+1)->other buf} in ONE basic
// block so the scheduler interleaves GEMM1's MFMA/X-compute under
// softmax's exp2/shuffle latency chain. Latency-bound at fixed 28%
// occupancy (4-block paths all spill, R2-R6) -> buy ILP not TLP.
// LDS 51968: floor(163840/51968)=3 keeps the PROVEN 3-block register
// budget (~168/wave). GEMM2-before-GEMM1 program order keeps h2-read
// waits off the fresh writes (write->read distance = 1 iteration).
// ============================================================
#define H2_PITCH 144               // bytes/row (72 f16; 16B-aligned rows)
#define H2_SIZE  (16*144)          // 2304 B / buffer
#define W1L_OFF  0
#define W2L_OFF  (16*1024)
#define C1L_OFF  (24*1024)
#define H2_BASE  24832
#define QL_OFF   (H2_BASE + 8*H2_SIZE)   // 24832 + 18432 = 43264 (2 bufs/wave)
#define QL_PITCH 272                     // 256 B data + 16 B pad (16B aligned rows)
#define LDS_TOTAL (QL_OFF + 32*QL_PITCH) // 51968 -> still 3 blocks/CU

__global__ __launch_bounds__(256, 3)
void k_main(const int* __restrict__ idx, const float* __restrict__ b2,
            const float* __restrict__ o_p_fea,
            const char* __restrict__ ws, float* __restrict__ out)
{
  const unsigned short* kp2h = (const unsigned short*)(ws + KP2H_OFF);
  const float* uT = (const float*)(ws + UT_OFF);

  __shared__ __align__(16) char lds[LDS_TOTAL];
  const int t = threadIdx.x;
  const int wave = t >> 6, l = t & 63;
  const int quad = l >> 4, row = l & 15;
  char* h2base = lds + H2_BASE + wave * (2 * H2_SIZE);

  const int slot = blockIdx.x * 4 + wave;   // 0..9999 wave-slots
  const int gid0 = slot * 4;                // 4 group-tasks per wave
  const int nloc = row >> 3;

  // ---- stage weight fragments into block-shared LDS (24832 B) ----
  {
    const uint4* src = (const uint4*)(ws + W1F_OFF);
    uint4* dst = (uint4*)lds;
    #pragma unroll
    for (int i = 0; i < 7; ++i) {
      const int e = t + i * 256;
      if (e < WSTAGE_BYTES / 16) dst[e] = src[e];
    }
  }

  // ---- inline q-projection for this block's 32 points ----
  {
    const int tile = wave >> 1;
    const int mt0 = (wave & 1) * 4;
    const int nq = blockIdx.x * 32 + tile * 16 + row;
    const float* feab = o_p_fea + (size_t)nq * 128;
    f32x4 qa[4];
    #pragma unroll
    for (int mt = 0; mt < 4; ++mt) qa[mt] = (f32x4){0.f, 0.f, 0.f, 0.f};
    #pragma unroll
    for (int kt = 0; kt < 4; ++kt) {
      f32x4 fa = *(const f32x4*)(feab + kt*32 + quad*8);
      f32x4 fb = *(const f32x4*)(feab + kt*32 + quad*8 + 4);
      FragU bu;
      bu.u[0] = pk_f16(fa[0], fa[1]);
      bu.u[1] = pk_f16(fa[2], fa[3]);
      bu.u[2] = pk_f16(fb[0], fb[1]);
      bu.u[3] = pk_f16(fb[2], fb[3]);
      #pragma unroll
      for (int mt = 0; mt < 4; ++mt) {
        FragU wf;
        wf.q = *(const uint4*)(ws + WQF_OFF + (((kt*8 + mt0 + mt)*64 + l) * 16));
        qa[mt] = __builtin_amdgcn_mfma_f32_16x16x32_f16(wf.v, bu.v, qa[mt], 0, 0, 0);
      }
    }
    char* lq = lds + QL_OFF + (tile*16 + row) * QL_PITCH;
    #pragma unroll
    for (int mt = 0; mt < 4; ++mt) {
      uint2 pp;
      pp.x = pk_f16(qa[mt][0], qa[mt][1]);
      pp.y = pk_f16(qa[mt][2], qa[mt][3]);
      *(uint2*)(lq + (mt0 + mt)*32 + quad*8) = pp;
    }
  }

  // prefetch this wave's 4 groups' gather indices (row pattern for kp2h)
  int mr4[4];
  #pragma unroll
  for (int g = 0; g < 4; ++g) mr4[g] = idx[(gid0 + g)*16 + row];

  __syncthreads();   // weights + q staged

  f32x4 c1r[4];
  #pragma unroll
  for (int jt = 0; jt < 4; ++jt)
    c1r[jt] = *(const f32x4*)(lds + C1L_OFF + (jt*16 + quad*4)*4);
  float b2r[4];
  #pragma unroll
  for (int nt = 0; nt < 4; ++nt) b2r[nt] = b2[row + nt*16] * LOG2E;

  // ---- helper lambdas ----
  auto qload = [&](int g, uint4* qp) {
    const char* lqr = lds + QL_OFF + (wave*8 + g*2 + nloc) * QL_PITCH;
    #pragma unroll
    for (int kt = 0; kt < 4; ++kt)
      qp[kt] = *(const uint4*)(lqr + (kt*4 + quad)*16);
  };
  auto kload = [&](int g, uint4* kf) {
    const uint4* kr = (const uint4*)(kp2h + (size_t)mr4[g] * 128);
    #pragma unroll
    for (int kt = 0; kt < 4; ++kt) kf[kt] = kr[kt*4 + quad];
  };
  auto run_gemm1 = [&](const uint4* kf, const uint4* qp, char* h2dst) {
    f32x4 a1[4];
    #pragma unroll
    for (int jt = 0; jt < 4; ++jt) a1[jt] = c1r[jt];
    #pragma unroll
    for (int kt = 0; kt < 4; ++kt) {
      const f16x8 kv = __builtin_bit_cast(f16x8, kf[kt]);
      const f16x8 qv = __builtin_bit_cast(f16x8, qp[kt]);
      f16x8 z = {};
      f16x8 x = __builtin_elementwise_max((f16x8)(kv - qv), z);
      FragU xf;
      xf.v = x;
      #pragma unroll
      for (int jt = 0; jt < 4; ++jt) {
        const f16x8 wf = *(const f16x8*)(lds + W1L_OFF + (kt*4+jt)*1024 + l*16);
        a1[jt] = __builtin_amdgcn_mfma_f32_16x16x32_f16(wf, xf.v, a1[jt], 0, 0, 0);
      }
    }
    #pragma unroll
    for (int jt = 0; jt < 4; ++jt) {
      uint2 pp;
      pp.x = pk_f16(a1[jt][0], a1[jt][1]);
      pp.y = pk_f16(a1[jt][2], a1[jt][3]);
      f16x4 h = __builtin_bit_cast(f16x4, pp);
      f16x4 z4 = {};
      h = __builtin_elementwise_max(h, z4);
      pp = __builtin_bit_cast(uint2, h);
      *(uint2*)(h2dst + row*H2_PITCH + (jt*16 + quad*4)*2) = pp;
    }
  };
  auto run_gemm2 = [&](const char* h2src, const f32x4* u4, int gid) {
    f32x4 a2[4];
    #pragma unroll
    for (int nt = 0; nt < 4; ++nt) a2[nt] = (f32x4){0.f, 0.f, 0.f, 0.f};
    #pragma unroll
    for (int kt2 = 0; kt2 < 2; ++kt2) {
      const f16x8 af = *(const f16x8*)(h2src + row*H2_PITCH + kt2*64 + quad*16);
      #pragma unroll
      for (int nt = 0; nt < 4; ++nt) {
        const f16x8 wf = *(const f16x8*)(lds + W2L_OFF + (kt2*4+nt)*1024 + l*16);
        a2[nt] = __builtin_amdgcn_mfma_f32_16x16x32_f16(af, wf, a2[nt], 0, 0, 0);
      }
    }
    float bi0 = 0.f, bi1 = 0.f, bi2 = 0.f, bi3 = 0.f;
    #pragma unroll
    for (int nt = 0; nt < 4; ++nt) {
      const float e0 = exp2_fast(a2[nt][0] + b2r[nt]);
      const float e1 = exp2_fast(a2[nt][1] + b2r[nt]);
      const float e2 = exp2_fast(a2[nt][2] + b2r[nt]);
      const float e3 = exp2_fast(a2[nt][3] + b2r[nt]);
      float s = e0 + e1 + e2 + e3;
      s += __shfl_xor(s, 16);
      const float rs = __builtin_amdgcn_rcpf(s);
      bi0 = fmaf(e0 * rs, u4[0][nt], bi0);
      bi1 = fmaf(e1 * rs, u4[1][nt], bi1);
      bi2 = fmaf(e2 * rs, u4[2][nt], bi2);
      bi3 = fmaf(e3 * rs, u4[3][nt], bi3);
    }
    float bi[4];
    bi[0] = row16_sum(bi0);
    bi[1] = row16_sum(bi1);
    bi[2] = row16_sum(bi2);
    bi[3] = row16_sum(bi3);
    const float eb0 = exp2_fast(bi[0]), eb1 = exp2_fast(bi[1]);
    const float eb2 = exp2_fast(bi[2]), eb3 = exp2_fast(bi[3]);
    float sb = eb0 + eb1 + eb2 + eb3;
    sb += __shfl_xor(sb, 16);
    const float rsb = __builtin_amdgcn_rcpf(sb);
    if (row < 4) {
      const float vsel = row == 0 ? eb0 : row == 1 ? eb1 : row == 2 ? eb2 : eb3;
      out[gid*16 + quad*4 + row] = vsel * rsb;
    }
  };

  // ---- pipeline prologue: GEMM1(0) -> buf0; prefetch group-1 operands ----
  int msc[4];
  #pragma unroll
  for (int rg = 0; rg < 4; ++rg) msc[rg] = idx[gid0*16 + quad*4 + rg];
  uint4 kfn[4], qpn[4];
  kload(0, kfn);
  qload(0, qpn);
  run_gemm1(kfn, qpn, h2base);
  int msn[4];
  #pragma unroll
  for (int rg = 0; rg < 4; ++rg) msn[rg] = idx[(gid0+1)*16 + quad*4 + rg];
  kload(1, kfn);
  qload(1, qpn);

  // ---- pipelined main loop: GEMM2(g) || GEMM1(g+1) ----
  #pragma unroll 1
  for (int g = 0; g < 3; ++g) {
    // uT for current group (consumed in softmax; issued early)
    f32x4 u4[4];
    #pragma unroll
    for (int rg = 0; rg < 4; ++rg)
      u4[rg] = *(const f32x4*)(uT + (size_t)msc[rg] * 64 + row * 4);

    // GEMM2 + softmax + store for group g (reads buf written last iter)
    run_gemm2(h2base + (g & 1) * H2_SIZE, u4, gid0 + g);

    // GEMM1 for group g+1 into the other buffer (scheduler interleaves
    // its MFMA/X-compute under softmax's exp2/shuffle chain)
    run_gemm1(kfn, qpn, h2base + ((g + 1) & 1) * H2_SIZE);

    // rotate indices; prefetch group g+2 operands
    #pragma unroll
    for (int rg = 0; rg < 4; ++rg) msc[rg] = msn[rg];
    if (g < 2) {
      #pragma unroll
      for (int rg = 0; rg < 4; ++rg) msn[rg] = idx[(gid0+g+2)*16 + quad*4 + rg];
      kload(g + 2, kfn);
      qload(g + 2, qpn);
    }
  }

  // ---- epilogue: GEMM2(3) ----
  {
    f32x4 u4[4];
    #pragma unroll
    for (int rg = 0; rg < 4; ++rg)
      u4[rg] = *(const f32x4*)(uT + (size_t)msc[rg] * 64 + row * 4);
    run_gemm2(h2base + H2_SIZE, u4, gid0 + 3);
  }
}

// ============================================================
extern "C" void kernel_launch(void* const* d_in, const int* in_sizes, int n_in,
                              void* d_out, int out_size, void* d_ws, size_t ws_size,
                              hipStream_t stream)
{
  const float* sp_fea  = (const float*)d_in[0];
  const float* sp_xyz  = (const float*)d_in[1];
  const float* o_p_fea = (const float*)d_in[2];
  // d_in[3] p_xyz unused by reference
  const float* Wq    = (const float*)d_in[4];
  const float* bq    = (const float*)d_in[5];
  const float* Wk    = (const float*)d_in[6];
  const float* bk    = (const float*)d_in[7];
  const float* Wv    = (const float*)d_in[8];
  const float* bv    = (const float*)d_in[9];
  const float* Wp1   = (const float*)d_in[10];
  const float* bp1   = (const float*)d_in[11];
  const float* gp    = (const float*)d_in[12];
  const float* betap = (const float*)d_in[13];
  const float* mp    = (const float*)d_in[14];
  const float* vp    = (const float*)d_in[15];
  const float* Wp2   = (const float*)d_in[16];
  const float* bp2   = (const float*)d_in[17];
  const float* g1    = (const float*)d_in[18];
  const float* beta1 = (const float*)d_in[19];
  const float* m1    = (const float*)d_in[20];
  const float* v1    = (const float*)d_in[21];
  const float* W1    = (const float*)d_in[22];
  const float* b1    = (const float*)d_in[23];
  const float* g2    = (const float*)d_in[24];
  const float* beta2 = (const float*)d_in[25];
  const float* m2    = (const float*)d_in[26];
  const float* v2    = (const float*)d_in[27];
  const float* W2    = (const float*)d_in[28];
  const float* b2    = (const float*)d_in[29];
  const int* c2p_idx_abs = (const int*)d_in[30];
  // d_in[31..34] unused by reference

  char* ws = (char*)d_ws;
  float* out = (float*)d_out;

  hipLaunchKernelGGL(k_prep, dim3(1015), dim3(256), 0, stream,
                     sp_fea, sp_xyz, Wk, bk, Wv, bv, Wp1, bp1, gp, betap, mp, vp,
                     Wp2, bp2, g1, beta1, m1, v1, bq,
                     Wq, W1, W2, g2, v2, b1, m2, beta2, ws);
  hipLaunchKernelGGL(k_main, dim3(2500), dim3(256), 0, stream,
                     c2p_idx_abs, b2, o_p_fea, ws, out);
}